// Round 4
// baseline (1972.300 us; speedup 1.0000x reference)
//
#include <hip/hip_runtime.h>

#define N    512
#define EPS  1e-4f
#define RL   128        // LDS-resident rows (rows 0..127, always < n since n >= 256)
#define KW   32         // LDS rows per wave
#define KR   96         // register rows per thread (wave owns rows 128+4k+w)
#define MSTR 256        // mlds row stride in uints (f16x2 packed, 512 cols)

// LDS uints: mlds[128*256] | uu[512]f | vf[512]f | vpk[256] | red[4*512]f
#define LDS_U   (RL*MSTR + 512 + 512 + 256 + 4*512)
#define LDS_BYTES (LDS_U * 4)

union U32H { unsigned int u; _Float16 h[2]; };
__device__ inline float h_lo(unsigned int x){ U32H t; t.u = x; return (float)t.h[0]; }
__device__ inline float h_hi(unsigned int x){ U32H t; t.u = x; return (float)t.h[1]; }
__device__ inline unsigned int h_pk(float a, float b){ U32H t; t.h[0]=(_Float16)a; t.h[1]=(_Float16)b; return t.u; }

typedef _Float16 half2v __attribute__((ext_vector_type(2)));
__device__ inline float dot2(unsigned int m, unsigned int v, float c){
#if __has_builtin(__builtin_amdgcn_fdot2)
    return __builtin_amdgcn_fdot2(__builtin_bit_cast(half2v, m), __builtin_bit_cast(half2v, v), c, false);
#else
    return c + h_lo(m)*h_lo(v) + h_hi(m)*h_hi(v);
#endif
}

__global__ __launch_bounds__(256) __attribute__((amdgpu_waves_per_eu(1, 1)))
void k_sink(const float* __restrict__ A, const int* __restrict__ nrows,
            float* __restrict__ out)
{
    extern __shared__ unsigned int lds[];
    unsigned int* mlds = lds;
    float* uu = (float*)(lds + RL*MSTR);
    float* vf = uu + 512;
    unsigned int* vpk = (unsigned int*)(vf + 512);
    float* red = (float*)(vpk + 256);

    const int b = blockIdx.x;
    const int n = nrows[b];
    const int t = threadIdx.x;
    const int w = t >> 6, l = t & 63;
    const int c8 = l * 8;                    // this thread's 8 columns
    const size_t base = (size_t)b * (N*N);

    bool cok[8];
#pragma unroll
    for (int j = 0; j < 8; ++j) cok[j] = (c8 + j) < n;

    // ---------------- load + convert: (A+eps) -> f16x2, zero outside n x n ----------------
    unsigned int mreg[KR][4];
#pragma unroll
    for (int k = 0; k < KR; ++k) {
        int r = RL + 4*k + w;
        const float4* p = (const float4*)(A + base + (size_t)r*N + c8);
        float4 a0 = p[0], a1 = p[1];
        bool rok = r < n;
        float e0 = (rok && cok[0]) ? a0.x + EPS : 0.f;
        float e1 = (rok && cok[1]) ? a0.y + EPS : 0.f;
        float e2 = (rok && cok[2]) ? a0.z + EPS : 0.f;
        float e3 = (rok && cok[3]) ? a0.w + EPS : 0.f;
        float e4 = (rok && cok[4]) ? a1.x + EPS : 0.f;
        float e5 = (rok && cok[5]) ? a1.y + EPS : 0.f;
        float e6 = (rok && cok[6]) ? a1.z + EPS : 0.f;
        float e7 = (rok && cok[7]) ? a1.w + EPS : 0.f;
        mreg[k][0] = h_pk(e0, e1); mreg[k][1] = h_pk(e2, e3);
        mreg[k][2] = h_pk(e4, e5); mreg[k][3] = h_pk(e6, e7);
    }
#pragma unroll
    for (int k = 0; k < KW; ++k) {
        int r = KW*w + k;                    // rows 0..127, always < n
        const float4* p = (const float4*)(A + base + (size_t)r*N + c8);
        float4 a0 = p[0], a1 = p[1];
        uint4 q;
        q.x = h_pk(cok[0] ? a0.x + EPS : 0.f, cok[1] ? a0.y + EPS : 0.f);
        q.y = h_pk(cok[2] ? a0.z + EPS : 0.f, cok[3] ? a0.w + EPS : 0.f);
        q.z = h_pk(cok[4] ? a1.x + EPS : 0.f, cok[5] ? a1.y + EPS : 0.f);
        q.w = h_pk(cok[6] ? a1.z + EPS : 0.f, cok[7] ? a1.w + EPS : 0.f);
        *(uint4*)(mlds + r*MSTR + 4*l) = q;
    }
    uu[t] = 1.f; uu[t + 256] = 1.f;          // rows >= n contribute 0 via M zeros
    __syncthreads();

    // ---------------- 10 Sinkhorn steps = 5 x (col, row) ----------------
    for (int it = 0; it < 5; ++it) {
        // --- col step: vf[c] = 1 / sum_r uu[r]*M[r,c] ---
        float acc[8] = {0,0,0,0,0,0,0,0};
#pragma unroll
        for (int k = 0; k < KR; ++k) {
            float ur = uu[RL + 4*k + w];     // wave-uniform LDS broadcast
#pragma unroll
            for (int j = 0; j < 4; ++j) {
                unsigned int m = mreg[k][j];
                acc[2*j]   += ur * h_lo(m);
                acc[2*j+1] += ur * h_hi(m);
            }
        }
#pragma unroll
        for (int k = 0; k < KW; ++k) {
            int r = KW*w + k;
            float ur = uu[r];
            uint4 q = *(const uint4*)(mlds + r*MSTR + 4*l);
            acc[0] += ur * h_lo(q.x); acc[1] += ur * h_hi(q.x);
            acc[2] += ur * h_lo(q.y); acc[3] += ur * h_hi(q.y);
            acc[4] += ur * h_lo(q.z); acc[5] += ur * h_hi(q.z);
            acc[6] += ur * h_lo(q.w); acc[7] += ur * h_hi(q.w);
        }
        {
            float4* rw = (float4*)(red + w*512 + c8);
            rw[0] = make_float4(acc[0], acc[1], acc[2], acc[3]);
            rw[1] = make_float4(acc[4], acc[5], acc[6], acc[7]);
        }
        __syncthreads();
        {
            int ca = 2*t, cb = 2*t + 1;
            float s0 = red[ca] + red[512 + ca] + red[1024 + ca] + red[1536 + ca];
            float s1 = red[cb] + red[512 + cb] + red[1024 + cb] + red[1536 + cb];
            float v0 = (ca < n) ? 1.f / s0 : 0.f;
            float v1 = (cb < n) ? 1.f / s1 : 0.f;
            vf[ca] = v0; vf[cb] = v1;
            vpk[t] = h_pk(v0, v1);
        }
        __syncthreads();

        // --- row step: uu[r] = 1 / sum_c M[r,c]*vf[c] ---
        unsigned int vp[4];
        {
            uint4 q = *(const uint4*)(vpk + 4*l);
            vp[0] = q.x; vp[1] = q.y; vp[2] = q.z; vp[3] = q.w;
        }
#pragma unroll
        for (int k = 0; k < KR; ++k) {
            float p = 0.f;
#pragma unroll
            for (int j = 0; j < 4; ++j) p = dot2(mreg[k][j], vp[j], p);
#pragma unroll
            for (int o = 32; o; o >>= 1) p += __shfl_xor(p, o, 64);
            int r = RL + 4*k + w;
            if (l == (k & 63)) uu[r] = (r < n) ? 1.f / p : 0.f;
        }
        {   // LDS rows: 2 threads per row, rotated start -> 2-way (free) banks
            int r = t >> 1, hf = t & 1;
            const unsigned int* rowp = mlds + r*MSTR + hf*128;
            const unsigned int* vq   = vpk + hf*128;
            float p0 = 0.f, p1 = 0.f;
#pragma unroll
            for (int j = 0; j < 128; j += 2) {
                int q0 = (r + j) & 127;
                int q1 = (r + j + 1) & 127;
                p0 = dot2(rowp[q0], vq[q0], p0);
                p1 = dot2(rowp[q1], vq[q1], p1);
            }
            float p = p0 + p1;
            p += __shfl_xor(p, 1, 64);
            if (hf == 0) uu[r] = 1.f / p;    // rows < 128 always < n
        }
        __syncthreads();
    }

    // ---------------- epilogue: out = M * u9[r] * v8[c] (fp32 stores) ----------------
    float v8[8];
#pragma unroll
    for (int j = 0; j < 8; ++j) v8[j] = vf[c8 + j];
#pragma unroll
    for (int k = 0; k < KR; ++k) {
        int r = RL + 4*k + w;
        float ur = uu[r];                    // 0 for r >= n
        float4 o0, o1;
        o0.x = h_lo(mreg[k][0]) * ur * v8[0];  o0.y = h_hi(mreg[k][0]) * ur * v8[1];
        o0.z = h_lo(mreg[k][1]) * ur * v8[2];  o0.w = h_hi(mreg[k][1]) * ur * v8[3];
        o1.x = h_lo(mreg[k][2]) * ur * v8[4];  o1.y = h_hi(mreg[k][2]) * ur * v8[5];
        o1.z = h_lo(mreg[k][3]) * ur * v8[6];  o1.w = h_hi(mreg[k][3]) * ur * v8[7];
        float4* po = (float4*)(out + base + (size_t)r*N + c8);
        po[0] = o0; po[1] = o1;
    }
#pragma unroll
    for (int k = 0; k < KW; ++k) {
        int r = KW*w + k;
        float ur = uu[r];
        uint4 q = *(const uint4*)(mlds + r*MSTR + 4*l);
        float4 o0, o1;
        o0.x = h_lo(q.x) * ur * v8[0];  o0.y = h_hi(q.x) * ur * v8[1];
        o0.z = h_lo(q.y) * ur * v8[2];  o0.w = h_hi(q.y) * ur * v8[3];
        o1.x = h_lo(q.z) * ur * v8[4];  o1.y = h_hi(q.z) * ur * v8[5];
        o1.z = h_lo(q.w) * ur * v8[6];  o1.w = h_hi(q.w) * ur * v8[7];
        float4* po = (float4*)(out + base + (size_t)r*N + c8);
        po[0] = o0; po[1] = o1;
    }
}

extern "C" void kernel_launch(void* const* d_in, const int* in_sizes, int n_in,
                              void* d_out, int out_size, void* d_ws, size_t ws_size,
                              hipStream_t stream) {
    const float* A     = (const float*)d_in[0];
    const int*   nrows = (const int*)d_in[1];
    float*       out   = (float*)d_out;
    const int    B     = in_sizes[1];        // 128

    hipFuncSetAttribute(reinterpret_cast<const void*>(k_sink),
                        hipFuncAttributeMaxDynamicSharedMemorySize, LDS_BYTES);

    k_sink<<<B, 256, LDS_BYTES, stream>>>(A, nrows, out);
}